// Round 13
// baseline (185.562 us; speedup 1.0000x reference)
//
#include <hip/hip_runtime.h>

// RelationAwareDiscriminator:
//   out[b,u,v] = sigmoid( sum_{d,e} UE[u,d] * R[r[b],d,e] * VE[v,e] )
// Dedup: out[b] depends on b only via r[b] (64 distinct relations).
// R13: copy-shaped storing kernel. The only 6.5 TB/s movers measured (R5
// copy, fillBuffer) are barrier-free, LDS-free, high-TLP, steady-issue.
// K2 replicates that: 2048 blocks (rel x 4ut x 8vt), zero LDS, zero
// barriers, 16 waves/CU, 8x4 register microtile off L2-resident ws data,
// NT replica stores, exit. K1 precomputes T/VEt/match-lists (proven).

#define BATCH 512
#define DIM   128
#define NRELS 64
#define NTHR  256

typedef float floatx4 __attribute__((ext_vector_type(4)));

// ws layout (floats)
#define T_ELEMS   ((size_t)NRELS * DIM * BATCH)      // [rel][e][u]
#define VET_OFF   (T_ELEMS)                          // [e][v] 128x512
#define CNT_OFF   (T_ELEMS + (size_t)DIM * BATCH)    // 64 ints
#define LIST_OFF  (CNT_OFF + 64)                     // [rel][512] ints
#define WS_NEED   ((LIST_OFF + (size_t)NRELS * BATCH) * 4)

// ---------------- K1: T blocks (bid<512), match lists (512), VEt (513..520)
__global__ __launch_bounds__(NTHR, 2)
void rad_prep_kernel(const int* __restrict__ u_idx,
                     const int* __restrict__ v_idx,
                     const int* __restrict__ r_idx,
                     const float* __restrict__ nodes,   // [100000][128]
                     const float* __restrict__ rels,    // [64][128][128]
                     float* __restrict__ ws)
{
    const int bid = (int)blockIdx.x;
    const int t   = (int)threadIdx.x;

    if (bid == NRELS * 8) {
        __shared__ int s_cnt[NRELS];
        int* counts = (int*)(ws + CNT_OFF);
        int* lists  = (int*)(ws + LIST_OFF);
        if (t < NRELS) s_cnt[t] = 0;
        __syncthreads();
        for (int i = t; i < BATCH; i += NTHR) {
            const int rel = r_idx[i];
            const int pos = atomicAdd(&s_cnt[rel], 1);
            lists[rel * BATCH + pos] = i;
        }
        __syncthreads();
        if (t < NRELS) counts[t] = s_cnt[t];
        return;
    }
    if (bid > NRELS * 8) {
        const int v0 = (bid - NRELS * 8 - 1) * 64;
        float* VEt = ws + VET_OFF;
        for (int i = t; i < 64 * (DIM / 4); i += NTHR) {
            const int row = i & 63;
            const int dc  = i >> 6;   // 0..31
            const float4 val = *reinterpret_cast<const float4*>(
                nodes + (size_t)v_idx[v0 + row] * DIM + dc * 4);
            VEt[(dc * 4 + 0) * BATCH + v0 + row] = val.x;
            VEt[(dc * 4 + 1) * BATCH + v0 + row] = val.y;
            VEt[(dc * 4 + 2) * BATCH + v0 + row] = val.z;
            VEt[(dc * 4 + 3) * BATCH + v0 + row] = val.w;
        }
        return;
    }

    // ---- T block: T[rel][e][u] = sum_d UE[u,d] * R[rel][d,e]
    const int rel = bid >> 3;
    const int ut0 = (bid & 7) * 64;

    __shared__ __align__(16) float UEsT[DIM * 64];  // [d][u] 32 KB
    __shared__ __align__(16) float Rs[16 * DIM];    // [dd][e] 8 KB

    const int tu = t >> 4;   // 0..15
    const int tx = t & 15;   // 0..15

    for (int i = t; i < 64 * (DIM / 4); i += NTHR) {
        const int row = i & 63;
        const int dc  = i >> 6;
        const float4 val = *reinterpret_cast<const float4*>(
            nodes + (size_t)u_idx[ut0 + row] * DIM + dc * 4);
        UEsT[(dc * 4 + 0) * 64 + row] = val.x;
        UEsT[(dc * 4 + 1) * 64 + row] = val.y;
        UEsT[(dc * 4 + 2) * 64 + row] = val.z;
        UEsT[(dc * 4 + 3) * 64 + row] = val.w;
    }

    float accA[4][8];
    #pragma unroll
    for (int i = 0; i < 4; ++i)
        #pragma unroll
        for (int j = 0; j < 8; ++j) accA[i][j] = 0.f;

    const float* Rbase = rels + (size_t)rel * DIM * DIM;
    for (int dch = 0; dch < DIM / 16; ++dch) {
        __syncthreads();
        for (int i = t; i < 16 * (DIM / 4); i += NTHR) {
            const int rr = i >> 5;
            const int cc = i & 31;
            *reinterpret_cast<float4*>(Rs + rr * DIM + cc * 4) =
                *reinterpret_cast<const float4*>(
                    Rbase + (size_t)(dch * 16 + rr) * DIM + cc * 4);
        }
        __syncthreads();
        #pragma unroll
        for (int dd = 0; dd < 16; ++dd) {
            const int d = dch * 16 + dd;
            const float4 a  = *reinterpret_cast<const float4*>(UEsT + d * 64 + tu * 4);
            const float4 b0 = *reinterpret_cast<const float4*>(Rs + dd * DIM + tx * 4);
            const float4 b1 = *reinterpret_cast<const float4*>(Rs + dd * DIM + 64 + tx * 4);
            const float av[4] = {a.x, a.y, a.z, a.w};
            const float bv[8] = {b0.x, b0.y, b0.z, b0.w, b1.x, b1.y, b1.z, b1.w};
            #pragma unroll
            for (int i = 0; i < 4; ++i)
                #pragma unroll
                for (int j = 0; j < 8; ++j)
                    accA[i][j] = fmaf(av[i], bv[j], accA[i][j]);
        }
    }

    #pragma unroll
    for (int j = 0; j < 8; ++j) {
        const int e = (j < 4) ? (tx * 4 + j) : (64 + tx * 4 + (j - 4));
        float4 w4 = make_float4(accA[0][j], accA[1][j], accA[2][j], accA[3][j]);
        *reinterpret_cast<float4*>(
            ws + ((size_t)rel * DIM + e) * BATCH + ut0 + tu * 4) = w4;
    }
}

// ---------------- K2: LDS-free, barrier-free 128x64 tile, 8x4 microtile.
__global__ __launch_bounds__(NTHR, 4)
void rad_tile_kernel(const float* __restrict__ ws,
                     float* __restrict__ out)       // [512][512][512]
{
    // Decode (assume XCD = bid%8): x = bid&7, k = bid>>3 (0..255),
    // rel = k>>2, rr = k&3; ut = rr (0..3, 128 rows), vt = x (0..7, 64 cols).
    // Per XCD: vt fixed -> VEt slice (32 KB) resident; rel-major order ->
    // T[rel] (256 KB) reused across its 4 ut-blocks. Store bytes per XCD =
    // Sum_rel 4*mc[rel]*32 KB, identical for all XCDs.
    const int bid = (int)blockIdx.x;
    const int x   = bid & 7;
    const int k   = bid >> 3;
    const int rel = k >> 2;
    const int ut0 = (k & 3) * 128;
    const int vt0 = x * 64;

    const int* counts = (const int*)(ws + CNT_OFF);
    const int* lists  = (const int*)(ws + LIST_OFF) + rel * BATCH;
    const int  mc     = counts[rel];
    if (mc == 0) return;

    const int t  = (int)threadIdx.x;
    const int tu = t >> 4;   // 0..15: u rows ut0 + tu*8 .. +7
    const int tx = t & 15;   // 0..15: v cols vt0 + tx*4 .. +3

    const float* Tcol = ws + (size_t)rel * DIM * BATCH + ut0 + tu * 8;
    const float* Vcol = ws + VET_OFF + vt0 + tx * 4;

    float acc[8][4];
    #pragma unroll
    for (int i = 0; i < 8; ++i)
        #pragma unroll
        for (int j = 0; j < 4; ++j) acc[i][j] = 0.f;

    #pragma unroll 4
    for (int e = 0; e < DIM; ++e) {
        const float4 t0 = *reinterpret_cast<const float4*>(Tcol + (size_t)e * BATCH);
        const float4 t1 = *reinterpret_cast<const float4*>(Tcol + (size_t)e * BATCH + 4);
        const float4 vq = *reinterpret_cast<const float4*>(Vcol + (size_t)e * BATCH);
        const float tr[8] = {t0.x, t0.y, t0.z, t0.w, t1.x, t1.y, t1.z, t1.w};
        const float vc[4] = {vq.x, vq.y, vq.z, vq.w};
        #pragma unroll
        for (int i = 0; i < 8; ++i)
            #pragma unroll
            for (int j = 0; j < 4; ++j)
                acc[i][j] = fmaf(tr[i], vc[j], acc[i][j]);
    }

    floatx4 sg[8];
    #pragma unroll
    for (int i = 0; i < 8; ++i) {
        sg[i].x = 1.f / (1.f + __expf(-acc[i][0]));
        sg[i].y = 1.f / (1.f + __expf(-acc[i][1]));
        sg[i].z = 1.f / (1.f + __expf(-acc[i][2]));
        sg[i].w = 1.f / (1.f + __expf(-acc[i][3]));
    }

    // NT replica stores; no barriers, no trailing waits.
    for (int m = 0; m < mc; ++m) {
        const int bb = lists[m];
        float* obase = out + ((size_t)bb << 18) + vt0 + tx * 4;
        #pragma unroll
        for (int i = 0; i < 8; ++i) {
            __builtin_nontemporal_store(
                sg[i], reinterpret_cast<floatx4*>(
                           obase + ((size_t)(ut0 + tu * 8 + i) << 9)));
        }
    }
}

// ---------------- Fallback: proven R7 fused kernel (142.7 us) if ws too small
__device__ __forceinline__ void lds_barrier() {
    asm volatile("s_waitcnt lgkmcnt(0)" ::: "memory");
    __builtin_amdgcn_s_barrier();
    __builtin_amdgcn_sched_barrier(0);
}

__global__ __launch_bounds__(NTHR, 2)
void rad_fused_kernel(const int* __restrict__ u_idx,
                      const int* __restrict__ v_idx,
                      const int* __restrict__ r_idx,
                      const float* __restrict__ nodes,
                      const float* __restrict__ rels,
                      float* __restrict__ out)
{
    const int bid = (int)blockIdx.x;
    const int rel = ((bid & 7) << 3) | (bid >> 6);
    const int ut0 = ((bid >> 3) & 7) * 64;

    __shared__ int s_match[BATCH];
    __shared__ int s_mc;
    __shared__ __align__(16) float s_TsT[DIM * 64];
    __shared__ __align__(16) float s_buf[DIM * 64 + 16 * DIM];

    const int t  = (int)threadIdx.x;
    const int tu = t >> 4;
    const int tx = t & 15;

    if (t == 0) s_mc = 0;
    __syncthreads();
    for (int i = t; i < BATCH; i += NTHR) {
        if (r_idx[i] == rel) {
            int p = atomicAdd(&s_mc, 1);
            s_match[p] = i;
        }
    }

    float* UEsT = s_buf;
    float* Rs   = s_buf + DIM * 64;

    for (int i = t; i < 64 * (DIM / 4); i += NTHR) {
        const int row = i & 63;
        const int dc  = i >> 6;
        const float4 val = *reinterpret_cast<const float4*>(
            nodes + (size_t)u_idx[ut0 + row] * DIM + dc * 4);
        UEsT[(dc * 4 + 0) * 64 + row] = val.x;
        UEsT[(dc * 4 + 1) * 64 + row] = val.y;
        UEsT[(dc * 4 + 2) * 64 + row] = val.z;
        UEsT[(dc * 4 + 3) * 64 + row] = val.w;
    }
    __syncthreads();
    const int mc = s_mc;
    if (mc == 0) return;

    float accA[4][8];
    #pragma unroll
    for (int i = 0; i < 4; ++i)
        #pragma unroll
        for (int j = 0; j < 8; ++j) accA[i][j] = 0.f;

    const float* Rbase = rels + (size_t)rel * DIM * DIM;
    for (int dch = 0; dch < DIM / 16; ++dch) {
        for (int i = t; i < 16 * (DIM / 4); i += NTHR) {
            const int rr = i >> 5;
            const int cc = i & 31;
            *reinterpret_cast<float4*>(Rs + rr * DIM + cc * 4) =
                *reinterpret_cast<const float4*>(
                    Rbase + (size_t)(dch * 16 + rr) * DIM + cc * 4);
        }
        lds_barrier();
        #pragma unroll
        for (int dd = 0; dd < 16; ++dd) {
            const int d = dch * 16 + dd;
            const float4 a  = *reinterpret_cast<const float4*>(UEsT + d * 64 + tu * 4);
            const float4 b0 = *reinterpret_cast<const float4*>(Rs + dd * DIM + tx * 4);
            const float4 b1 = *reinterpret_cast<const float4*>(Rs + dd * DIM + 64 + tx * 4);
            const float av[4] = {a.x, a.y, a.z, a.w};
            const float bv[8] = {b0.x, b0.y, b0.z, b0.w, b1.x, b1.y, b1.z, b1.w};
            #pragma unroll
            for (int i = 0; i < 4; ++i)
                #pragma unroll
                for (int j = 0; j < 8; ++j)
                    accA[i][j] = fmaf(av[i], bv[j], accA[i][j]);
        }
        lds_barrier();
    }

    #pragma unroll
    for (int j = 0; j < 8; ++j) {
        const int e = (j < 4) ? (tx * 4 + j) : (64 + tx * 4 + (j - 4));
        #pragma unroll
        for (int i = 0; i < 4; ++i)
            s_TsT[e * 64 + tu * 4 + i] = accA[i][j];
    }

    float* VEsT = s_buf;
    for (int vt = 0; vt < BATCH / 64; ++vt) {
        lds_barrier();
        for (int i = t; i < 64 * (DIM / 4); i += NTHR) {
            const int row = i & 63;
            const int ec  = i >> 6;
            const float4 val = *reinterpret_cast<const float4*>(
                nodes + (size_t)v_idx[vt * 64 + row] * DIM + ec * 4);
            VEsT[(ec * 4 + 0) * 64 + row] = val.x;
            VEsT[(ec * 4 + 1) * 64 + row] = val.y;
            VEsT[(ec * 4 + 2) * 64 + row] = val.z;
            VEsT[(ec * 4 + 3) * 64 + row] = val.w;
        }
        lds_barrier();

        float acc[4][4];
        #pragma unroll
        for (int i = 0; i < 4; ++i)
            #pragma unroll
            for (int j = 0; j < 4; ++j) acc[i][j] = 0.f;

        #pragma unroll 8
        for (int e = 0; e < DIM; ++e) {
            const float4 a = *reinterpret_cast<const float4*>(s_TsT + e * 64 + tu * 4);
            const float4 b = *reinterpret_cast<const float4*>(VEsT  + e * 64 + tx * 4);
            const float av[4] = {a.x, a.y, a.z, a.w};
            const float bv[4] = {b.x, b.y, b.z, b.w};
            #pragma unroll
            for (int i = 0; i < 4; ++i)
                #pragma unroll
                for (int j = 0; j < 4; ++j)
                    acc[i][j] = fmaf(av[i], bv[j], acc[i][j]);
        }

        floatx4 sg[4];
        #pragma unroll
        for (int i = 0; i < 4; ++i) {
            sg[i].x = 1.f / (1.f + __expf(-acc[i][0]));
            sg[i].y = 1.f / (1.f + __expf(-acc[i][1]));
            sg[i].z = 1.f / (1.f + __expf(-acc[i][2]));
            sg[i].w = 1.f / (1.f + __expf(-acc[i][3]));
        }

        for (int m = 0; m < mc; ++m) {
            const int bb = s_match[m];
            float* obase = out + (size_t)bb * BATCH * BATCH + vt * 64 + tx * 4;
            #pragma unroll
            for (int i = 0; i < 4; ++i) {
                __builtin_nontemporal_store(
                    sg[i], reinterpret_cast<floatx4*>(
                               obase + (size_t)(ut0 + tu * 4 + i) * BATCH));
            }
        }
    }
}

extern "C" void kernel_launch(void* const* d_in, const int* in_sizes, int n_in,
                              void* d_out, int out_size, void* d_ws, size_t ws_size,
                              hipStream_t stream) {
    const int*   u_idx = (const int*)d_in[0];
    const int*   v_idx = (const int*)d_in[1];
    const int*   r_idx = (const int*)d_in[2];
    const float* nodes = (const float*)d_in[3];
    const float* rels  = (const float*)d_in[4];
    float* out = (float*)d_out;

    if (ws_size >= WS_NEED) {
        float* ws = (float*)d_ws;
        rad_prep_kernel<<<dim3(NRELS * 8 + 1 + 8), dim3(NTHR), 0, stream>>>(
            u_idx, v_idx, r_idx, nodes, rels, ws);
        rad_tile_kernel<<<dim3(2048), dim3(NTHR), 0, stream>>>(ws, out);
    } else {
        rad_fused_kernel<<<dim3(NRELS * 8), dim3(NTHR), 0, stream>>>(
            u_idx, v_idx, r_idx, nodes, rels, out);
    }
}

// Round 14
// 156.466 us; speedup vs baseline: 1.1860x; 1.1860x over previous
//
#include <hip/hip_runtime.h>

// RelationAwareDiscriminator:
//   out[b,u,v] = sigmoid( sum_{d,e} UE[u,d] * R[r[b],d,e] * VE[v,e] )
// Dedup: out[b] depends on b only via r[b] (64 distinct relations).
// R14: STORE-TERMINAL fused kernel. vmcnt is a FIFO: any load issued after
// stores forces a full store drain (dynamic mc loop -> compiler must use
// vmcnt(0)). All prior fused variants re-staged VE after each tile's store
// burst -> 8 serialized drains per block. Here the whole 64x256 half-slab
// is accumulated in registers (acc[16][4]) BEFORE any store; the replica
// burst is the last thing the block does (match-list reads are LDS ->
// lgkmcnt, independent). 1024 blocks = 2 rounds: round-2 compute overlaps
// round-1 store drain.

#define BATCH 512
#define DIM   128
#define NRELS 64
#define NTHR  256

typedef float floatx4 __attribute__((ext_vector_type(4)));

// LDS-only barrier: orders ds ops without draining global stores.
__device__ __forceinline__ void lds_barrier() {
    asm volatile("s_waitcnt lgkmcnt(0)" ::: "memory");
    __builtin_amdgcn_s_barrier();
    __builtin_amdgcn_sched_barrier(0);
}

__global__ __launch_bounds__(NTHR, 2)
void rad_term_kernel(const int* __restrict__ u_idx,
                     const int* __restrict__ v_idx,
                     const int* __restrict__ r_idx,
                     const float* __restrict__ nodes,   // [100000][128]
                     const float* __restrict__ rels,    // [64][128][128]
                     float* __restrict__ out)           // [512][512][512]
{
    // 1024 blocks. XCD decode (assume XCD = bid%8): all 16 blocks of a rel
    // (8 ut x 2 vh) land on ONE XCD, rel-major order -> R/UE/v-row reads
    // L2-shared (R7's proven locality scheme, extended).
    const int bid = (int)blockIdx.x;
    const int rel = ((bid & 7) << 3) | (bid >> 7);   // 0..63
    const int ut0 = ((bid >> 4) & 7) * 64;           // 0..448
    const int vh  = (bid >> 3) & 1;                  // 0/1: 256-col half

    __shared__ int s_match[BATCH];
    __shared__ int s_mc;
    __shared__ __align__(16) float TsT[DIM * 64];              // [e][u], 32 KB
    __shared__ __align__(16) float s_buf[DIM * 64 + 16 * DIM]; // 40 KB scratch

    const int t  = (int)threadIdx.x;
    const int tu = t >> 4;   // phase A: u group of 4
    const int tx = t & 15;   // phase A: e group

    if (t == 0) s_mc = 0;
    __syncthreads();
    for (int i = t; i < BATCH; i += NTHR) {
        if (r_idx[i] == rel) {
            int p = atomicAdd(&s_mc, 1);
            s_match[p] = i;
        }
    }

    float* UEsT = s_buf;               // [d][u] 128x64, 32 KB (phase A)
    float* Rs   = s_buf + DIM * 64;    // [dd][e] 16x128, 8 KB (phase A)

    // Gather u-embedding rows, store transposed [d][u].
    for (int i = t; i < 64 * (DIM / 4); i += NTHR) {
        const int row = i & 63;
        const int dc  = i >> 6;
        const float4 val = *reinterpret_cast<const float4*>(
            nodes + (size_t)u_idx[ut0 + row] * DIM + dc * 4);
        UEsT[(dc * 4 + 0) * 64 + row] = val.x;
        UEsT[(dc * 4 + 1) * 64 + row] = val.y;
        UEsT[(dc * 4 + 2) * 64 + row] = val.z;
        UEsT[(dc * 4 + 3) * 64 + row] = val.w;
    }
    __syncthreads();
    const int mc = s_mc;
    if (mc == 0) return;

    // ---------------- Phase A (R7 verbatim): TsT[e][u] = UE.R
    float accA[4][8];
    #pragma unroll
    for (int i = 0; i < 4; ++i)
        #pragma unroll
        for (int j = 0; j < 8; ++j) accA[i][j] = 0.f;

    const float* Rbase = rels + (size_t)rel * DIM * DIM;
    for (int dch = 0; dch < DIM / 16; ++dch) {
        for (int i = t; i < 16 * (DIM / 4); i += NTHR) {
            const int rr = i >> 5;
            const int cc = i & 31;
            *reinterpret_cast<float4*>(Rs + rr * DIM + cc * 4) =
                *reinterpret_cast<const float4*>(
                    Rbase + (size_t)(dch * 16 + rr) * DIM + cc * 4);
        }
        __syncthreads();
        #pragma unroll
        for (int dd = 0; dd < 16; ++dd) {
            const int d = dch * 16 + dd;
            const float4 a  = *reinterpret_cast<const float4*>(UEsT + d * 64 + tu * 4);
            const float4 b0 = *reinterpret_cast<const float4*>(Rs + dd * DIM + tx * 4);
            const float4 b1 = *reinterpret_cast<const float4*>(Rs + dd * DIM + 64 + tx * 4);
            const float av[4] = {a.x, a.y, a.z, a.w};
            const float bv[8] = {b0.x, b0.y, b0.z, b0.w, b1.x, b1.y, b1.z, b1.w};
            #pragma unroll
            for (int i = 0; i < 4; ++i)
                #pragma unroll
                for (int j = 0; j < 8; ++j)
                    accA[i][j] = fmaf(av[i], bv[j], accA[i][j]);
        }
        __syncthreads();
    }

    #pragma unroll
    for (int j = 0; j < 8; ++j) {
        const int e = (j < 4) ? (tx * 4 + j) : (64 + tx * 4 + (j - 4));
        #pragma unroll
        for (int i = 0; i < 4; ++i)
            TsT[e * 64 + tu * 4 + i] = accA[i][j];
    }

    // ---------------- Phase B: full 64x256 half-slab in registers.
    // Wave w owns rows rt=w*16..+15; lane l owns cols ct=l*4..+3 (of 256).
    const int w  = t >> 6;
    const int rt = w * 16;
    const int ct = (t & 63) * 4;
    float* VEs = s_buf;   // [16][256] 16 KB per e-chunk, reuses scratch

    float acc[16][4];
    #pragma unroll
    for (int r = 0; r < 16; ++r)
        #pragma unroll
        for (int c = 0; c < 4; ++c) acc[r][c] = 0.f;

    for (int ec = 0; ec < 8; ++ec) {
        __syncthreads();   // prior VEs readers done (1st iter: TsT written)
        // Stage VEs[ee][v] = VE[vh*256+v][ec*16+ee]; 1024 float4 loads.
        #pragma unroll
        for (int kk = 0; kk < 4; ++kk) {
            const int i  = t + kk * NTHR;
            const int v  = i & 255;
            const int c4 = i >> 8;          // 0..3
            const float4 val = *reinterpret_cast<const float4*>(
                nodes + (size_t)v_idx[vh * 256 + v] * DIM + ec * 16 + c4 * 4);
            VEs[(c4 * 4 + 0) * 256 + v] = val.x;
            VEs[(c4 * 4 + 1) * 256 + v] = val.y;
            VEs[(c4 * 4 + 2) * 256 + v] = val.z;
            VEs[(c4 * 4 + 3) * 256 + v] = val.w;
        }
        __syncthreads();

        #pragma unroll 2
        for (int ee = 0; ee < 16; ++ee) {
            const int e = ec * 16 + ee;
            const float4 t0 = *reinterpret_cast<const float4*>(TsT + e * 64 + rt);
            const float4 t1 = *reinterpret_cast<const float4*>(TsT + e * 64 + rt + 4);
            const float4 t2 = *reinterpret_cast<const float4*>(TsT + e * 64 + rt + 8);
            const float4 t3 = *reinterpret_cast<const float4*>(TsT + e * 64 + rt + 12);
            const float4 bv = *reinterpret_cast<const float4*>(VEs + ee * 256 + ct);
            const float tr[16] = {t0.x, t0.y, t0.z, t0.w,
                                  t1.x, t1.y, t1.z, t1.w,
                                  t2.x, t2.y, t2.z, t2.w,
                                  t3.x, t3.y, t3.z, t3.w};
            const float bc[4] = {bv.x, bv.y, bv.z, bv.w};
            #pragma unroll
            for (int r = 0; r < 16; ++r)
                #pragma unroll
                for (int c = 0; c < 4; ++c)
                    acc[r][c] = fmaf(tr[r], bc[c], acc[r][c]);
        }
    }

    // Sigmoid into vector regs.
    floatx4 sg[16];
    #pragma unroll
    for (int r = 0; r < 16; ++r) {
        sg[r].x = 1.f / (1.f + __expf(-acc[r][0]));
        sg[r].y = 1.f / (1.f + __expf(-acc[r][1]));
        sg[r].z = 1.f / (1.f + __expf(-acc[r][2]));
        sg[r].w = 1.f / (1.f + __expf(-acc[r][3]));
    }

    // ---------------- TERMINAL store burst: nothing follows these stores.
    // Per (m,r): one wave instruction = 64 lanes x 16 B = 1 KB contiguous.
    // s_match reads are LDS (lgkmcnt) - independent of the vmcnt FIFO.
    for (int m = 0; m < mc; ++m) {
        const int bb = s_match[m];
        float* obase = out + ((size_t)bb << 18)
                           + ((size_t)(ut0 + rt) << 9) + vh * 256 + ct;
        #pragma unroll
        for (int r = 0; r < 16; ++r) {
            __builtin_nontemporal_store(
                sg[r], reinterpret_cast<floatx4*>(obase + ((size_t)r << 9)));
        }
    }
}

extern "C" void kernel_launch(void* const* d_in, const int* in_sizes, int n_in,
                              void* d_out, int out_size, void* d_ws, size_t ws_size,
                              hipStream_t stream) {
    const int*   u_idx = (const int*)d_in[0];
    const int*   v_idx = (const int*)d_in[1];
    const int*   r_idx = (const int*)d_in[2];
    const float* nodes = (const float*)d_in[3];
    const float* rels  = (const float*)d_in[4];
    float* out = (float*)d_out;

    dim3 grid(NRELS * 8 * 2); // 1024 blocks: rel x 8 ut x 2 v-halves
    dim3 block(NTHR);
    rad_term_kernel<<<grid, block, 0, stream>>>(u_idx, v_idx, r_idx, nodes, rels, out);
}